// Round 7
// baseline (199.475 us; speedup 1.0000x reference)
//
#include <hip/hip_runtime.h>
#include <hip/hip_bf16.h>

typedef __attribute__((ext_vector_type(8))) short short8v;   // 8 bf16 = 4 VGPR
typedef __attribute__((ext_vector_type(4))) float f32x4;

// ---------- packed weights (written by prep_kernel every launch) ----------
__device__ __align__(16) float g_w0T[256 * 512];                       // fp32 [c][j] j<256 mean-w, j>=256 pixel-w
__device__ __align__(16) unsigned short g_wp1h[8 * 8 * 64 * 8], g_wp1l[8 * 8 * 64 * 8]; // L1 A-frags hi/lo
__device__ __align__(16) unsigned short g_wp2h[4 * 4 * 64 * 8], g_wp2l[4 * 4 * 64 * 8]; // L2
__device__ __align__(16) unsigned short g_wp3h[2 * 2 * 64 * 8], g_wp3l[2 * 2 * 64 * 8]; // L3

// ---------- helpers ----------
__device__ __forceinline__ float lrelu(float x) { return x >= 0.f ? x : 0.01f * x; }
__device__ __forceinline__ unsigned short f2us(float x) {
    __hip_bfloat16 h = __float2bfloat16(x);
    return *(unsigned short*)&h;
}
__device__ __forceinline__ float us2f(unsigned short u) {
    union { unsigned i; float f; } c; c.i = ((unsigned)u) << 16; return c.f;
}
__device__ __forceinline__ void split_bf(float v, unsigned short& hi, unsigned short& lo) {
    hi = f2us(v); lo = f2us(v - us2f(hi));
}
__device__ __forceinline__ void pack_hilo(const f32x4& a, uint2& ph, uint2& pl) {
    unsigned short h[4], lo[4];
#pragma unroll
    for (int i = 0; i < 4; ++i) {
        float v = lrelu(a[i]);
        h[i] = f2us(v); lo[i] = f2us(v - us2f(h[i]));
    }
    ph.x = (unsigned)h[0] | ((unsigned)h[1] << 16);
    ph.y = (unsigned)h[2] | ((unsigned)h[3] << 16);
    pl.x = (unsigned)lo[0] | ((unsigned)lo[1] << 16);
    pl.y = (unsigned)lo[2] | ((unsigned)lo[3] << 16);
}

// ---------- prep: transpose w0 (fp32), pack w1..w3 into hi/lo MFMA A-frags ----------
__global__ __launch_bounds__(256) void prep_kernel(
    const float* __restrict__ w0, const float* __restrict__ w1,
    const float* __restrict__ w2, const float* __restrict__ w3)
{
    int id = blockIdx.x * 256 + threadIdx.x;
    int stride = gridDim.x * 256;
    for (int i = id; i < 256 * 512; i += stride) {        // w0T[c][j] fp32
        int c = i >> 9, j = i & 511;
        g_w0T[i] = (j < 256) ? w0[j * 512 + c] : w0[(j - 256) * 512 + 256 + c];
    }
    // A-frag: lane l holds A[row = l&15][k = (l>>4)*8 + e]
    for (int i = id; i < 8 * 8 * 64 * 8; i += stride) {   // L1: 128x256
        int e = i & 7, l = (i >> 3) & 63, k0 = (i >> 9) & 7, m = i >> 12;
        int oc = m * 16 + (l & 15), c = k0 * 32 + ((l >> 4) * 8) + e;
        unsigned short hi, lo; split_bf(w1[oc * 256 + c], hi, lo);
        g_wp1h[i] = hi; g_wp1l[i] = lo;
    }
    for (int i = id; i < 4 * 4 * 64 * 8; i += stride) {   // L2: 64x128
        int e = i & 7, l = (i >> 3) & 63, k0 = (i >> 9) & 3, m = i >> 11;
        int oc = m * 16 + (l & 15), c = k0 * 32 + ((l >> 4) * 8) + e;
        unsigned short hi, lo; split_bf(w2[oc * 128 + c], hi, lo);
        g_wp2h[i] = hi; g_wp2l[i] = lo;
    }
    for (int i = id; i < 2 * 2 * 64 * 8; i += stride) {   // L3: 32x64
        int e = i & 7, l = (i >> 3) & 63, k0 = (i >> 9) & 1, m = i >> 10;
        int oc = m * 16 + (l & 15), c = k0 * 32 + ((l >> 4) * 8) + e;
        unsigned short hi, lo; split_bf(w3[oc * 64 + c], hi, lo);
        g_wp3h[i] = hi; g_wp3l[i] = lo;
    }
}

// ---------- a0 wide: A0f[b,pix,j] = w0T[:,j] @ cand[b,:,pix], j in [0,512) fp32 ----------
__global__ __launch_bounds__(512) void a0_wide_kernel(
    const float* __restrict__ cand, float* __restrict__ A0f)
{
    __shared__ float row[256][20];
    int b = blockIdx.x / 20, u = blockIdx.x % 20;
    int t = threadIdx.x;
    if (t < 256) {
        const float* src = cand + (size_t)(b * 256 + t) * 400 + u * 20;
#pragma unroll
        for (int q = 0; q < 5; ++q) {
            float4 v = ((const float4*)src)[q];
            row[t][q * 4 + 0] = v.x; row[t][q * 4 + 1] = v.y;
            row[t][q * 4 + 2] = v.z; row[t][q * 4 + 3] = v.w;
        }
    }
    __syncthreads();
    float acc[20];
#pragma unroll
    for (int v = 0; v < 20; ++v) acc[v] = 0.f;
    for (int c = 0; c < 256; ++c) {
        float wv = g_w0T[c * 512 + t];        // lane-coalesced over t (both halves)
        const float* rp = row[c];
#pragma unroll
        for (int v = 0; v < 20; ++v) acc[v] += wv * rp[v];
    }
    float* dst = A0f + (size_t)(b * 400 + u * 20) * 512 + t;
#pragma unroll
    for (int v = 0; v < 20; ++v) dst[(size_t)v * 512] = acc[v];
}

// ---------- main: blocks 0..31 = template, 32..9279 = candidate patches ----------
// LDS (17408 B -> 8 blocks/CU @ 32-wave cap):
//   h0 half-buffer [16 p][128 c] bf16 swz: hi @0 (4K), lo @4096 (4K) -- reused for both K-halves
//   h1 [16][128]: hi @8192 (4K), lo @12288 (4K)
//   overlays on dead h0 after L1: h2 hi @0 (2K), lo @2048 (2K); h3 f32 [16][32] @4096 (2K); wn @6144
//   template-only: patchL [256][16] f32 @0 (16K, dead before h0/h1 writes), meanp @16384 (1K)
__global__ __launch_bounds__(256, 8) void main_kernel(
    const float* __restrict__ tf, const float* __restrict__ cand,
    const float* __restrict__ w4, const float* __restrict__ A0,
    float* __restrict__ out)
{
    __shared__ __align__(16) char smem[17408];
    const int OFF_H0HI = 0, OFF_H0LO = 4096;
    const int OFF_H1HI = 8192, OFF_H1LO = 12288;
    const int OFF_H2HI = 0, OFF_H2LO = 2048;
    const int OFF_H3 = 4096, OFF_WN = 6144, OFF_MEAN = 16384;

    int blk = blockIdx.x, t = threadIdx.x;
    int l = t & 63, w = t >> 6;
    bool is_tpl = blk < 32;
    float patch[16], hv[16];
    int b, r = 0;

    if (!is_tpl) {
        int idx0 = blk - 32;
        int idx = (idx0 & 7) * 1156 + (idx0 >> 3);   // XCD swizzle: 9248 = 8*1156 (bijective)
        b = idx / 289; r = idx % 289;
        int y = r / 17, x = r % 17;
        const float* csrc = cand + (size_t)(b * 256 + t) * 400 + y * 20 + x;
        const float* af = A0 + (size_t)(b * 400 + y * 20 + x) * 512;
        // batch-issue all 48 loads into registers (ILP), consume after
        float afm[16], afx[16];
#pragma unroll
        for (int p = 0; p < 16; ++p) {
            int po = ((p >> 2) * 20 + (p & 3)) * 512;
            afm[p] = af[po + t];
            afx[p] = af[po + 256 + t];
        }
#pragma unroll
        for (int p = 0; p < 16; ++p) patch[p] = csrc[(p >> 2) * 20 + (p & 3)];
        float m0 = 0.f;
#pragma unroll
        for (int p = 0; p < 16; ++p) m0 += afm[p];
        m0 *= (1.f / 16.f);
#pragma unroll
        for (int p = 0; p < 16; ++p) hv[p] = lrelu(m0 + afx[p]);
    } else {
        b = blk;
        float* meanp = (float*)(smem + OFF_MEAN);
        float (*patchL)[16] = (float(*)[16])(smem);   // @0, 16K (dead before h0 writes)
        const float* src = tf + (size_t)(b * 256 + t) * 16;
        float s = 0.f;
#pragma unroll
        for (int p = 0; p < 16; ++p) {
            float v = src[p];
            patch[p] = v; patchL[t][p] = v; s += v;
        }
        meanp[t] = s * (1.f / 16.f);
        __syncthreads();
        float m0 = 0.f, accp[16];
#pragma unroll
        for (int p = 0; p < 16; ++p) accp[p] = 0.f;
        for (int c = 0; c < 256; ++c) {
            float wm = g_w0T[c * 512 + t];
            float wp = g_w0T[c * 512 + 256 + t];
            m0 += wm * meanp[c];
            const float* pr = patchL[c];
#pragma unroll
            for (int p = 0; p < 16; ++p) accp[p] += wp * pr[p];
        }
#pragma unroll
        for (int p = 0; p < 16; ++p) hv[p] = lrelu(m0 + accp[p]);
        __syncthreads();   // patchL reads complete before h0 overwrites region
    }

    // write channel (local row cl in [0,128)) of the h0 half-buffer
    auto write_h0 = [&](int cl) {
#pragma unroll
        for (int p = 0; p < 16; ++p) {
            unsigned short hi, lo; split_bf(hv[p], hi, lo);
            int byte = p * 256 + ((((cl >> 3) ^ (p & 7)) << 4)) + (cl & 7) * 2;
            *(unsigned short*)(smem + OFF_H0HI + byte) = hi;
            *(unsigned short*)(smem + OFF_H0LO + byte) = lo;
        }
    };

    int p_ = l & 63 & 15, q = l >> 4;
    f32x4 acc0 = {0.f, 0.f, 0.f, 0.f}, acc1 = {0.f, 0.f, 0.f, 0.f};
    const short8v* A1h = (const short8v*)g_wp1h;
    const short8v* A1l = (const short8v*)g_wp1l;

    // ---- layer 1 K-half a: channels 0..127 ----
    if (t < 128) write_h0(t);
    __syncthreads();
#pragma unroll
    for (int k0 = 0; k0 < 4; ++k0) {
        int off = p_ * 256 + ((((k0 * 4 + q) ^ (p_ & 7)) << 4));
        short8v bh = *(const short8v*)(smem + OFF_H0HI + off);
        short8v bl = *(const short8v*)(smem + OFF_H0LO + off);
        short8v ah0 = A1h[((2 * w) * 8 + k0) * 64 + l];
        short8v al0 = A1l[((2 * w) * 8 + k0) * 64 + l];
        short8v ah1 = A1h[((2 * w + 1) * 8 + k0) * 64 + l];
        short8v al1 = A1l[((2 * w + 1) * 8 + k0) * 64 + l];
        acc0 = __builtin_amdgcn_mfma_f32_16x16x32_bf16(ah0, bh, acc0, 0, 0, 0);
        acc0 = __builtin_amdgcn_mfma_f32_16x16x32_bf16(ah0, bl, acc0, 0, 0, 0);
        acc0 = __builtin_amdgcn_mfma_f32_16x16x32_bf16(al0, bh, acc0, 0, 0, 0);
        acc1 = __builtin_amdgcn_mfma_f32_16x16x32_bf16(ah1, bh, acc1, 0, 0, 0);
        acc1 = __builtin_amdgcn_mfma_f32_16x16x32_bf16(ah1, bl, acc1, 0, 0, 0);
        acc1 = __builtin_amdgcn_mfma_f32_16x16x32_bf16(al1, bh, acc1, 0, 0, 0);
    }
    __syncthreads();
    // ---- layer 1 K-half b: channels 128..255 ----
    if (t >= 128) write_h0(t - 128);
    __syncthreads();
#pragma unroll
    for (int k0 = 0; k0 < 4; ++k0) {
        int off = p_ * 256 + ((((k0 * 4 + q) ^ (p_ & 7)) << 4));
        short8v bh = *(const short8v*)(smem + OFF_H0HI + off);
        short8v bl = *(const short8v*)(smem + OFF_H0LO + off);
        int kg = 4 + k0;
        short8v ah0 = A1h[((2 * w) * 8 + kg) * 64 + l];
        short8v al0 = A1l[((2 * w) * 8 + kg) * 64 + l];
        short8v ah1 = A1h[((2 * w + 1) * 8 + kg) * 64 + l];
        short8v al1 = A1l[((2 * w + 1) * 8 + kg) * 64 + l];
        acc0 = __builtin_amdgcn_mfma_f32_16x16x32_bf16(ah0, bh, acc0, 0, 0, 0);
        acc0 = __builtin_amdgcn_mfma_f32_16x16x32_bf16(ah0, bl, acc0, 0, 0, 0);
        acc0 = __builtin_amdgcn_mfma_f32_16x16x32_bf16(al0, bh, acc0, 0, 0, 0);
        acc1 = __builtin_amdgcn_mfma_f32_16x16x32_bf16(ah1, bh, acc1, 0, 0, 0);
        acc1 = __builtin_amdgcn_mfma_f32_16x16x32_bf16(ah1, bl, acc1, 0, 0, 0);
        acc1 = __builtin_amdgcn_mfma_f32_16x16x32_bf16(al1, bh, acc1, 0, 0, 0);
    }
    // ---- layer 1 epilogue -> h1 ----
    {
        int gr0 = 2 * (2 * w) + (q >> 1), gr1 = 2 * (2 * w + 1) + (q >> 1);
        uint2 ph0, pl0, ph1, pl1;
        pack_hilo(acc0, ph0, pl0);
        pack_hilo(acc1, ph1, pl1);
        int e0 = p_ * 256 + ((gr0 ^ (p_ & 7)) << 4) + (q & 1) * 8;
        int e1 = p_ * 256 + ((gr1 ^ (p_ & 7)) << 4) + (q & 1) * 8;
        *(uint2*)(smem + OFF_H1HI + e0) = ph0;
        *(uint2*)(smem + OFF_H1LO + e0) = pl0;
        *(uint2*)(smem + OFF_H1HI + e1) = ph1;
        *(uint2*)(smem + OFF_H1LO + e1) = pl1;
    }
    __syncthreads();

    // ---- layer 2: [64x128]x[128x16]; wave w owns M-tile w ----
    {
        f32x4 acc = {0.f, 0.f, 0.f, 0.f};
        const short8v* A2h = (const short8v*)g_wp2h;
        const short8v* A2l = (const short8v*)g_wp2l;
#pragma unroll
        for (int k0 = 0; k0 < 4; ++k0) {
            int off = p_ * 256 + ((((k0 * 4 + q) ^ (p_ & 7)) << 4));
            short8v bh = *(const short8v*)(smem + OFF_H1HI + off);
            short8v bl = *(const short8v*)(smem + OFF_H1LO + off);
            short8v ah = A2h[(w * 4 + k0) * 64 + l];
            short8v al = A2l[(w * 4 + k0) * 64 + l];
            acc = __builtin_amdgcn_mfma_f32_16x16x32_bf16(ah, bh, acc, 0, 0, 0);
            acc = __builtin_amdgcn_mfma_f32_16x16x32_bf16(ah, bl, acc, 0, 0, 0);
            acc = __builtin_amdgcn_mfma_f32_16x16x32_bf16(al, bh, acc, 0, 0, 0);
        }
        int gr = 2 * w + (q >> 1);
        uint2 ph, pl;
        pack_hilo(acc, ph, pl);
        int e = p_ * 128 + ((gr ^ (p_ & 7)) << 4) + (q & 1) * 8;
        *(uint2*)(smem + OFF_H2HI + e) = ph;
        *(uint2*)(smem + OFF_H2LO + e) = pl;
    }
    __syncthreads();

    // ---- layer 3: [32x64]x[64x16]; waves 0,1; h3 stored fp32 ----
    if (w < 2) {
        f32x4 acc = {0.f, 0.f, 0.f, 0.f};
        const short8v* A3h = (const short8v*)g_wp3h;
        const short8v* A3l = (const short8v*)g_wp3l;
#pragma unroll
        for (int k0 = 0; k0 < 2; ++k0) {
            int off = p_ * 128 + ((((k0 * 4 + q) ^ (p_ & 7)) << 4));
            short8v bh = *(const short8v*)(smem + OFF_H2HI + off);
            short8v bl = *(const short8v*)(smem + OFF_H2LO + off);
            short8v ah = A3h[(w * 2 + k0) * 64 + l];
            short8v al = A3l[(w * 2 + k0) * 64 + l];
            acc = __builtin_amdgcn_mfma_f32_16x16x32_bf16(ah, bh, acc, 0, 0, 0);
            acc = __builtin_amdgcn_mfma_f32_16x16x32_bf16(ah, bl, acc, 0, 0, 0);
            acc = __builtin_amdgcn_mfma_f32_16x16x32_bf16(al, bh, acc, 0, 0, 0);
        }
#pragma unroll
        for (int rg = 0; rg < 4; ++rg) {
            float v = lrelu(acc[rg]);
            int oc = w * 16 + q * 4 + rg;
            *(float*)(smem + OFF_H3 + p_ * 128 + ((oc ^ (p_ & 7)) << 2)) = v;
        }
    }
    __syncthreads();

    // ---- layer 4 + wave-parallel softmax (lanes 0..15 of wave 0) ----
    float* wn = (float*)(smem + OFF_WN);
    if (t < 16) {
        float s4 = 0.f;
#pragma unroll
        for (int c = 0; c < 32; ++c)
            s4 += w4[c] * *(const float*)(smem + OFF_H3 + t * 128 + ((c ^ (t & 7)) << 2));
        float m = s4;
#pragma unroll
        for (int msk = 8; msk; msk >>= 1) m = fmaxf(m, __shfl_xor(m, msk));
        float e = __expf(s4 - m), sum = e;
#pragma unroll
        for (int msk = 8; msk; msk >>= 1) sum += __shfl_xor(sum, msk);
        wn[t] = e / sum;
    }
    __syncthreads();

    // ---- weighted pooling + store ----
    float accv = 0.f;
#pragma unroll
    for (int p = 0; p < 16; ++p) accv += patch[p] * wn[p];
    if (is_tpl) {
        out[b * 272 + t] = accv;
        if (t < 16) out[b * 272 + 256 + t] = wn[t];
    } else {
        out[8704 + (size_t)(b * 256 + t) * 289 + r] = accv;
    }
}

// ---------- launch ----------
extern "C" void kernel_launch(void* const* d_in, const int* in_sizes, int n_in,
                              void* d_out, int out_size, void* d_ws, size_t ws_size,
                              hipStream_t stream)
{
    const float* tf = (const float*)d_in[0];
    const float* cf = (const float*)d_in[1];
    const float* w0 = (const float*)d_in[2];
    const float* w1 = (const float*)d_in[3];
    const float* w2 = (const float*)d_in[4];
    const float* w3 = (const float*)d_in[5];
    const float* w4 = (const float*)d_in[6];
    float* out = (float*)d_out;
    float* A0f = (float*)d_ws;   // 32*400*512 fp32 = 26.2 MB (proven to fit, round 6)

    prep_kernel<<<680, 256, 0, stream>>>(w0, w1, w2, w3);
    a0_wide_kernel<<<32 * 20, 512, 0, stream>>>(cf, A0f);
    main_kernel<<<32 + 32 * 289, 256, 0, stream>>>(tf, cf, w4, A0f, out);
}

// Round 8
// 175.279 us; speedup vs baseline: 1.1380x; 1.1380x over previous
//
#include <hip/hip_runtime.h>
#include <hip/hip_bf16.h>

typedef __attribute__((ext_vector_type(8))) short short8v;   // 8 bf16 = 4 VGPR
typedef __attribute__((ext_vector_type(4))) float f32x4;

// ---------- packed weights (written by prep_kernel every launch) ----------
__device__ __align__(16) float g_w0T[256 * 512];                       // fp32 [c][j] j<256 mean-w, j>=256 pixel-w
__device__ __align__(16) unsigned short g_wp1h[8 * 8 * 64 * 8], g_wp1l[8 * 8 * 64 * 8]; // L1 A-frags hi/lo
__device__ __align__(16) unsigned short g_wp2h[4 * 4 * 64 * 8], g_wp2l[4 * 4 * 64 * 8]; // L2
__device__ __align__(16) unsigned short g_wp3h[2 * 2 * 64 * 8], g_wp3l[2 * 2 * 64 * 8]; // L3

// ---------- helpers ----------
__device__ __forceinline__ float lrelu(float x) { return x >= 0.f ? x : 0.01f * x; }
__device__ __forceinline__ unsigned short f2us(float x) {
    __hip_bfloat16 h = __float2bfloat16(x);
    return *(unsigned short*)&h;
}
__device__ __forceinline__ float us2f(unsigned short u) {
    union { unsigned i; float f; } c; c.i = ((unsigned)u) << 16; return c.f;
}
__device__ __forceinline__ void split_bf(float v, unsigned short& hi, unsigned short& lo) {
    hi = f2us(v); lo = f2us(v - us2f(hi));
}
__device__ __forceinline__ void pack_hilo(const f32x4& a, uint2& ph, uint2& pl) {
    unsigned short h[4], lo[4];
#pragma unroll
    for (int i = 0; i < 4; ++i) {
        float v = lrelu(a[i]);
        h[i] = f2us(v); lo[i] = f2us(v - us2f(h[i]));
    }
    ph.x = (unsigned)h[0] | ((unsigned)h[1] << 16);
    ph.y = (unsigned)h[2] | ((unsigned)h[3] << 16);
    pl.x = (unsigned)lo[0] | ((unsigned)lo[1] << 16);
    pl.y = (unsigned)lo[2] | ((unsigned)lo[3] << 16);
}

// ---------- prep: transpose w0 (fp32), pack w1..w3 into hi/lo MFMA A-frags ----------
__global__ __launch_bounds__(256) void prep_kernel(
    const float* __restrict__ w0, const float* __restrict__ w1,
    const float* __restrict__ w2, const float* __restrict__ w3)
{
    int id = blockIdx.x * 256 + threadIdx.x;
    int stride = gridDim.x * 256;
    for (int i = id; i < 256 * 512; i += stride) {        // w0T[c][j] fp32
        int c = i >> 9, j = i & 511;
        g_w0T[i] = (j < 256) ? w0[j * 512 + c] : w0[(j - 256) * 512 + 256 + c];
    }
    // A-frag: lane l holds A[row = l&15][k = (l>>4)*8 + e]
    for (int i = id; i < 8 * 8 * 64 * 8; i += stride) {   // L1: 128x256
        int e = i & 7, l = (i >> 3) & 63, k0 = (i >> 9) & 7, m = i >> 12;
        int oc = m * 16 + (l & 15), c = k0 * 32 + ((l >> 4) * 8) + e;
        unsigned short hi, lo; split_bf(w1[oc * 256 + c], hi, lo);
        g_wp1h[i] = hi; g_wp1l[i] = lo;
    }
    for (int i = id; i < 4 * 4 * 64 * 8; i += stride) {   // L2: 64x128
        int e = i & 7, l = (i >> 3) & 63, k0 = (i >> 9) & 3, m = i >> 11;
        int oc = m * 16 + (l & 15), c = k0 * 32 + ((l >> 4) * 8) + e;
        unsigned short hi, lo; split_bf(w2[oc * 128 + c], hi, lo);
        g_wp2h[i] = hi; g_wp2l[i] = lo;
    }
    for (int i = id; i < 2 * 2 * 64 * 8; i += stride) {   // L3: 32x64
        int e = i & 7, l = (i >> 3) & 63, k0 = (i >> 9) & 1, m = i >> 10;
        int oc = m * 16 + (l & 15), c = k0 * 32 + ((l >> 4) * 8) + e;
        unsigned short hi, lo; split_bf(w3[oc * 64 + c], hi, lo);
        g_wp3h[i] = hi; g_wp3l[i] = lo;
    }
}

// ---------- a0 wide: A0f[b,pix,j] = w0T[:,j] @ cand[b,:,pix], j in [0,512) fp32 ----------
// XCD-swizzled so batch b lands on the same XCD as main_kernel's consumers (b = idx/20 -> 4 b per XCD).
__global__ __launch_bounds__(512) void a0_wide_kernel(
    const float* __restrict__ cand, float* __restrict__ A0f)
{
    __shared__ float row[256][20];
    int i = blockIdx.x;
    int idx = (i & 7) * 80 + (i >> 3);          // 640 = 8*80, bijective
    int b = idx / 20, u = idx % 20;
    int t = threadIdx.x;
    if (t < 256) {
        const float* src = cand + (size_t)(b * 256 + t) * 400 + u * 20;
#pragma unroll
        for (int q = 0; q < 5; ++q) {
            float4 v = ((const float4*)src)[q];
            row[t][q * 4 + 0] = v.x; row[t][q * 4 + 1] = v.y;
            row[t][q * 4 + 2] = v.z; row[t][q * 4 + 3] = v.w;
        }
    }
    __syncthreads();
    float acc[20];
#pragma unroll
    for (int v = 0; v < 20; ++v) acc[v] = 0.f;
    for (int c = 0; c < 256; ++c) {
        float wv = g_w0T[c * 512 + t];        // lane-coalesced over t (both halves)
        const float* rp = row[c];
#pragma unroll
        for (int v = 0; v < 20; ++v) acc[v] += wv * rp[v];
    }
    float* dst = A0f + (size_t)(b * 400 + u * 20) * 512 + t;
#pragma unroll
    for (int v = 0; v < 20; ++v) dst[(size_t)v * 512] = acc[v];
}

// ---------- main: blocks 0..31 = template (P=1), 32..2367 = candidate groups of P=4 patches ----------
// LDS (49152 B -> 3 blocks/CU):
//   h0q (quarter-K) [64 rows][64 ch] bf16 swz: hi @0 (8K), lo @8192 (8K)
//   h1 [64 rows][128 ch] bf16 swz:            hi @16384 (16K), lo @32768 (16K)
//   m0 f32[4][256] @32768 (on h1lo; dead before L1 epilogue writes h1lo)
//   h2 [64][64] hi @0 / lo @8192 (overlay h0q, dead after L1)
//   h3 [64][32] f32 @16384 (overlay h1hi, dead after L2)
//   wn f32[64] @0 (overlay h2hi, dead after L3)
//   template overlays: patchL [256][16] f32 @0 (16K), meanp @16384 (1K)
__global__ __launch_bounds__(256) void main_kernel(
    const float* __restrict__ tf, const float* __restrict__ cand,
    const float* __restrict__ w4, const float* __restrict__ A0,
    float* __restrict__ out)
{
    __shared__ __align__(16) char smem[49152];
    const int OFF_H0HI = 0, OFF_H0LO = 8192;
    const int OFF_H1HI = 16384, OFF_H1LO = 32768;
    const int OFF_M0 = 32768;
    const int OFF_H2HI = 0, OFF_H2LO = 8192;
    const int OFF_H3 = 16384;

    int blk = blockIdx.x, t = threadIdx.x;
    int l = t & 63, w = t >> 6;
    int p_ = l & 15, q = l >> 4;
    int cl = t & 63, pp = t >> 6;
    bool is_tpl = blk < 32;

    float* m0_lds = (float*)(smem + OFF_M0);
    float* wn = (float*)smem;                 // valid after L3

    int b = 0, g = 0;
    int yy[4], xx[4], rr[4];
    int pixo[16];                             // pixel offsets for this thread's own patch (pp)
    const float* afb = nullptr;
    float afx[16];                            // pipelined pixel-half regs (cand)
    float hv_t[16], tpatch[16];               // template-only

    if (!is_tpl) {
        int i = blk - 32;
        int idx = (i & 7) * 292 + (i >> 3);   // 2336 = 8*292, bijective XCD swizzle
        b = idx / 73; g = idx % 73;
#pragma unroll
        for (int k = 0; k < 4; ++k) {
            int r = g * 4 + k; if (r > 288) r = 288;
            rr[k] = r; yy[k] = r / 17; xx[k] = r % 17;
        }
#pragma unroll
        for (int p = 0; p < 16; ++p)
            pixo[p] = (yy[pp] + (p >> 2)) * 20 + xx[pp] + (p & 3);
        afb = A0 + (size_t)b * 400 * 512;

        // phase 0: m0[pp][j=t] for all 4 patches (64 coalesced loads), plus q0 afx loads
        float m0v[4];
#pragma unroll
        for (int k = 0; k < 4; ++k) {
            float s = 0.f;
#pragma unroll
            for (int p = 0; p < 16; ++p) {
                int pix = (yy[k] + (p >> 2)) * 20 + xx[k] + (p & 3);
                s += afb[(size_t)pix * 512 + t];
            }
            m0v[k] = s * (1.f / 16.f);
        }
        {
            const float* axb = afb + 256 + cl;     // quarter 0: j = cl
#pragma unroll
            for (int p = 0; p < 16; ++p) afx[p] = axb[(size_t)pixo[p] * 512];
        }
#pragma unroll
        for (int k = 0; k < 4; ++k) m0_lds[k * 256 + t] = m0v[k];
        __syncthreads();
    } else {
        b = blk;
        float* meanp = (float*)(smem + 16384);
        float (*patchL)[16] = (float(*)[16])smem;
        const float* src = tf + (size_t)(b * 256 + t) * 16;
        float s = 0.f;
#pragma unroll
        for (int p = 0; p < 16; ++p) {
            float v = src[p];
            tpatch[p] = v; patchL[t][p] = v; s += v;
        }
        meanp[t] = s * (1.f / 16.f);
        __syncthreads();
        float m0 = 0.f, accp[16];
#pragma unroll
        for (int p = 0; p < 16; ++p) accp[p] = 0.f;
        for (int c = 0; c < 256; ++c) {
            float wm = g_w0T[c * 512 + t];
            float wp = g_w0T[c * 512 + 256 + t];
            m0 += wm * meanp[c];
            const float* pr = patchL[c];
#pragma unroll
            for (int p = 0; p < 16; ++p) accp[p] += wp * pr[p];
        }
#pragma unroll
        for (int p = 0; p < 16; ++p) hv_t[p] = lrelu(m0 + accp[p]);
        __syncthreads();                       // patchL reads done
        // zero h0q (rows 16..63 stay zero for all quarters)
        float4 z = {0.f, 0.f, 0.f, 0.f};
        float4* zp = (float4*)smem;
#pragma unroll
        for (int k = 0; k < 4; ++k) zp[t + k * 256] = z;
        __syncthreads();
    }

    // ---- stage quarter 0 ----
    if (!is_tpl) {
        float m0v = m0_lds[pp * 256 + cl];
#pragma unroll
        for (int p = 0; p < 16; ++p) {
            float h = lrelu(m0v + afx[p]);
            unsigned short hi, lo; split_bf(h, hi, lo);
            int byte = (pp * 16 + p) * 128 + ((((cl >> 3) ^ (p & 7))) << 4) + (cl & 7) * 2;
            *(unsigned short*)(smem + OFF_H0HI + byte) = hi;
            *(unsigned short*)(smem + OFF_H0LO + byte) = lo;
        }
    } else if (pp == 0) {                      // template: quarter qt staged by threads t>>6==qt
#pragma unroll
        for (int p = 0; p < 16; ++p) {
            unsigned short hi, lo; split_bf(hv_t[p], hi, lo);
            int byte = p * 128 + ((((cl >> 3) ^ (p & 7))) << 4) + (cl & 7) * 2;
            *(unsigned short*)(smem + OFF_H0HI + byte) = hi;
            *(unsigned short*)(smem + OFF_H0LO + byte) = lo;
        }
    }
    __syncthreads();

    // ---- layer 1: 4 quarters, per quarter 2 K-steps; wave w owns M-tiles 2w,2w+1 x N-tiles 0..3 ----
    f32x4 acc0[4], acc1[4];
#pragma unroll
    for (int n = 0; n < 4; ++n) { acc0[n] = (f32x4){0.f,0.f,0.f,0.f}; acc1[n] = (f32x4){0.f,0.f,0.f,0.f}; }
    const short8v* A1h = (const short8v*)g_wp1h;
    const short8v* A1l = (const short8v*)g_wp1l;

#pragma unroll
    for (int qt = 0; qt < 4; ++qt) {
        // async-stage: issue next quarter's pixel-half loads before this quarter's MFMAs
        if (!is_tpl && qt < 3) {
            const float* axb = afb + 256 + (qt + 1) * 64 + cl;
#pragma unroll
            for (int p = 0; p < 16; ++p) afx[p] = axb[(size_t)pixo[p] * 512];
        }
#pragma unroll
        for (int kk = 0; kk < 2; ++kk) {
            short8v bh[4], bl[4];
#pragma unroll
            for (int n = 0; n < 4; ++n) {
                int row = n * 16 + p_;
                int off = row * 128 + ((((kk * 4 + q) ^ (row & 7))) << 4);
                bh[n] = *(const short8v*)(smem + OFF_H0HI + off);
                bl[n] = *(const short8v*)(smem + OFF_H0LO + off);
            }
            int k0g = qt * 2 + kk;
            short8v ah0 = A1h[((2 * w) * 8 + k0g) * 64 + l];
            short8v al0 = A1l[((2 * w) * 8 + k0g) * 64 + l];
            short8v ah1 = A1h[((2 * w + 1) * 8 + k0g) * 64 + l];
            short8v al1 = A1l[((2 * w + 1) * 8 + k0g) * 64 + l];
#pragma unroll
            for (int n = 0; n < 4; ++n) {
                acc0[n] = __builtin_amdgcn_mfma_f32_16x16x32_bf16(ah0, bh[n], acc0[n], 0, 0, 0);
                acc0[n] = __builtin_amdgcn_mfma_f32_16x16x32_bf16(ah0, bl[n], acc0[n], 0, 0, 0);
                acc0[n] = __builtin_amdgcn_mfma_f32_16x16x32_bf16(al0, bh[n], acc0[n], 0, 0, 0);
                acc1[n] = __builtin_amdgcn_mfma_f32_16x16x32_bf16(ah1, bh[n], acc1[n], 0, 0, 0);
                acc1[n] = __builtin_amdgcn_mfma_f32_16x16x32_bf16(ah1, bl[n], acc1[n], 0, 0, 0);
                acc1[n] = __builtin_amdgcn_mfma_f32_16x16x32_bf16(al1, bh[n], acc1[n], 0, 0, 0);
            }
        }
        __syncthreads();                       // h0q consumed
        if (qt < 3) {
            if (!is_tpl) {
                float m0v = m0_lds[pp * 256 + (qt + 1) * 64 + cl];
#pragma unroll
                for (int p = 0; p < 16; ++p) {
                    float h = lrelu(m0v + afx[p]);
                    unsigned short hi, lo; split_bf(h, hi, lo);
                    int byte = (pp * 16 + p) * 128 + ((((cl >> 3) ^ (p & 7))) << 4) + (cl & 7) * 2;
                    *(unsigned short*)(smem + OFF_H0HI + byte) = hi;
                    *(unsigned short*)(smem + OFF_H0LO + byte) = lo;
                }
            } else if (pp == qt + 1) {
#pragma unroll
                for (int p = 0; p < 16; ++p) {
                    unsigned short hi, lo; split_bf(hv_t[p], hi, lo);
                    int byte = p * 128 + ((((cl >> 3) ^ (p & 7))) << 4) + (cl & 7) * 2;
                    *(unsigned short*)(smem + OFF_H0HI + byte) = hi;
                    *(unsigned short*)(smem + OFF_H0LO + byte) = lo;
                }
            }
            __syncthreads();
        }
    }

    // ---- layer 1 epilogue -> h1 ----
#pragma unroll
    for (int m2 = 0; m2 < 2; ++m2) {
        int gr = 2 * (2 * w + m2) + (q >> 1);
#pragma unroll
        for (int n = 0; n < 4; ++n) {
            uint2 ph, pl;
            pack_hilo(m2 ? acc1[n] : acc0[n], ph, pl);
            int row = n * 16 + p_;
            int e = row * 256 + ((gr ^ (row & 7)) << 4) + (q & 1) * 8;
            *(uint2*)(smem + OFF_H1HI + e) = ph;
            *(uint2*)(smem + OFF_H1LO + e) = pl;
        }
    }
    __syncthreads();

    // ---- layer 2: [64x128]x[128x64]; wave w owns M-tile w x N 0..3 ----
    {
        f32x4 acc[4];
#pragma unroll
        for (int n = 0; n < 4; ++n) acc[n] = (f32x4){0.f,0.f,0.f,0.f};
        const short8v* A2h = (const short8v*)g_wp2h;
        const short8v* A2l = (const short8v*)g_wp2l;
#pragma unroll
        for (int k0 = 0; k0 < 4; ++k0) {
            short8v bh[4], bl[4];
#pragma unroll
            for (int n = 0; n < 4; ++n) {
                int row = n * 16 + p_;
                int off = row * 256 + ((((k0 * 4 + q) ^ (row & 7))) << 4);
                bh[n] = *(const short8v*)(smem + OFF_H1HI + off);
                bl[n] = *(const short8v*)(smem + OFF_H1LO + off);
            }
            short8v ah = A2h[(w * 4 + k0) * 64 + l];
            short8v al = A2l[(w * 4 + k0) * 64 + l];
#pragma unroll
            for (int n = 0; n < 4; ++n) {
                acc[n] = __builtin_amdgcn_mfma_f32_16x16x32_bf16(ah, bh[n], acc[n], 0, 0, 0);
                acc[n] = __builtin_amdgcn_mfma_f32_16x16x32_bf16(ah, bl[n], acc[n], 0, 0, 0);
                acc[n] = __builtin_amdgcn_mfma_f32_16x16x32_bf16(al, bh[n], acc[n], 0, 0, 0);
            }
        }
        int gr = 2 * w + (q >> 1);
#pragma unroll
        for (int n = 0; n < 4; ++n) {
            uint2 ph, pl;
            pack_hilo(acc[n], ph, pl);
            int row = n * 16 + p_;
            int e = row * 128 + ((gr ^ (row & 7)) << 4) + (q & 1) * 8;
            *(uint2*)(smem + OFF_H2HI + e) = ph;
            *(uint2*)(smem + OFF_H2LO + e) = pl;
        }
    }
    __syncthreads();

    // ---- layer 3: [32x64]x[64x64]; waves 0,1 own M-tiles 0,1; h3 f32 ----
    if (w < 2) {
        f32x4 acc[4];
#pragma unroll
        for (int n = 0; n < 4; ++n) acc[n] = (f32x4){0.f,0.f,0.f,0.f};
        const short8v* A3h = (const short8v*)g_wp3h;
        const short8v* A3l = (const short8v*)g_wp3l;
#pragma unroll
        for (int k0 = 0; k0 < 2; ++k0) {
            short8v bh[4], bl[4];
#pragma unroll
            for (int n = 0; n < 4; ++n) {
                int row = n * 16 + p_;
                int off = row * 128 + ((((k0 * 4 + q) ^ (row & 7))) << 4);
                bh[n] = *(const short8v*)(smem + OFF_H2HI + off);
                bl[n] = *(const short8v*)(smem + OFF_H2LO + off);
            }
            short8v ah = A3h[(w * 2 + k0) * 64 + l];
            short8v al = A3l[(w * 2 + k0) * 64 + l];
#pragma unroll
            for (int n = 0; n < 4; ++n) {
                acc[n] = __builtin_amdgcn_mfma_f32_16x16x32_bf16(ah, bh[n], acc[n], 0, 0, 0);
                acc[n] = __builtin_amdgcn_mfma_f32_16x16x32_bf16(ah, bl[n], acc[n], 0, 0, 0);
                acc[n] = __builtin_amdgcn_mfma_f32_16x16x32_bf16(al, bh[n], acc[n], 0, 0, 0);
            }
        }
#pragma unroll
        for (int n = 0; n < 4; ++n) {
#pragma unroll
            for (int rg = 0; rg < 4; ++rg) {
                float v = lrelu(acc[n][rg]);
                int oc = w * 16 + q * 4 + rg;
                int row = n * 16 + p_;
                *(float*)(smem + OFF_H3 + row * 128 + ((oc ^ (row & 7)) << 2)) = v;
            }
        }
    }
    __syncthreads();

    // ---- layer 4 + softmax (64 scores = 4 patches x 16 pos, wave 0) ----
    if (t < 64) {
        float s4 = 0.f;
#pragma unroll
        for (int c = 0; c < 32; ++c)
            s4 += w4[c] * *(const float*)(smem + OFF_H3 + t * 128 + ((c ^ (t & 7)) << 2));
        float m = s4;
#pragma unroll
        for (int msk = 8; msk; msk >>= 1) m = fmaxf(m, __shfl_xor(m, msk));
        float e = __expf(s4 - m), sum = e;
#pragma unroll
        for (int msk = 8; msk; msk >>= 1) sum += __shfl_xor(sum, msk);
        wn[t] = e / sum;
    }
    __syncthreads();

    // ---- weighted pooling + store ----
    if (!is_tpl) {
        const float* cb = cand + (size_t)(b * 256 + t) * 400;
#pragma unroll
        for (int k = 0; k < 4; ++k) {
            float acc = 0.f;
#pragma unroll
            for (int p = 0; p < 16; ++p)
                acc += cb[(yy[k] + (p >> 2)) * 20 + xx[k] + (p & 3)] * wn[k * 16 + p];
            out[8704 + (size_t)(b * 256 + t) * 289 + rr[k]] = acc;
        }
    } else {
        float acc = 0.f;
#pragma unroll
        for (int p = 0; p < 16; ++p) acc += tpatch[p] * wn[p];
        out[b * 272 + t] = acc;
        if (t < 16) out[b * 272 + 256 + t] = wn[t];
    }
}

// ---------- launch ----------
extern "C" void kernel_launch(void* const* d_in, const int* in_sizes, int n_in,
                              void* d_out, int out_size, void* d_ws, size_t ws_size,
                              hipStream_t stream)
{
    const float* tf = (const float*)d_in[0];
    const float* cf = (const float*)d_in[1];
    const float* w0 = (const float*)d_in[2];
    const float* w1 = (const float*)d_in[3];
    const float* w2 = (const float*)d_in[4];
    const float* w3 = (const float*)d_in[5];
    const float* w4 = (const float*)d_in[6];
    float* out = (float*)d_out;
    float* A0f = (float*)d_ws;   // 32*400*512 fp32 = 26.2 MB (proven to fit, round 6)

    prep_kernel<<<680, 256, 0, stream>>>(w0, w1, w2, w3);
    a0_wide_kernel<<<32 * 20, 512, 0, stream>>>(cf, A0f);
    main_kernel<<<32 + 584 * 4, 256, 0, stream>>>(tf, cf, w4, A0f, out);
}

// Round 9
// 144.170 us; speedup vs baseline: 1.3836x; 1.2158x over previous
//
#include <hip/hip_runtime.h>
#include <hip/hip_bf16.h>

typedef __attribute__((ext_vector_type(8))) short short8v;   // 8 bf16 = 4 VGPR
typedef __attribute__((ext_vector_type(4))) float f32x4;

// ---------- packed weights (written by prep_kernel every launch) ----------
__device__ __align__(16) float g_w0T[256 * 512];                       // fp32 [c][j] j<256 mean-w, j>=256 pixel-w
__device__ __align__(16) unsigned short g_wa0h[32 * 8 * 64 * 8], g_wa0l[32 * 8 * 64 * 8]; // a0 A-frags [jt][k0][l][e]
__device__ __align__(16) unsigned short g_wp1h[8 * 8 * 64 * 8], g_wp1l[8 * 8 * 64 * 8]; // L1 A-frags hi/lo
__device__ __align__(16) unsigned short g_wp2h[4 * 4 * 64 * 8], g_wp2l[4 * 4 * 64 * 8]; // L2
__device__ __align__(16) unsigned short g_wp3h[2 * 2 * 64 * 8], g_wp3l[2 * 2 * 64 * 8]; // L3

// ---------- helpers ----------
__device__ __forceinline__ float lrelu(float x) { return x >= 0.f ? x : 0.01f * x; }
__device__ __forceinline__ unsigned short f2us(float x) {
    __hip_bfloat16 h = __float2bfloat16(x);
    return *(unsigned short*)&h;
}
__device__ __forceinline__ float us2f(unsigned short u) {
    union { unsigned i; float f; } c; c.i = ((unsigned)u) << 16; return c.f;
}
__device__ __forceinline__ void split_bf(float v, unsigned short& hi, unsigned short& lo) {
    hi = f2us(v); lo = f2us(v - us2f(hi));
}
__device__ __forceinline__ void pack_hilo(const f32x4& a, uint2& ph, uint2& pl) {
    unsigned short h[4], lo[4];
#pragma unroll
    for (int i = 0; i < 4; ++i) {
        float v = lrelu(a[i]);
        h[i] = f2us(v); lo[i] = f2us(v - us2f(h[i]));
    }
    ph.x = (unsigned)h[0] | ((unsigned)h[1] << 16);
    ph.y = (unsigned)h[2] | ((unsigned)h[3] << 16);
    pl.x = (unsigned)lo[0] | ((unsigned)lo[1] << 16);
    pl.y = (unsigned)lo[2] | ((unsigned)lo[3] << 16);
}

// ---------- prep: w0T fp32, a0 A-frags, L1..L3 A-frags (hi/lo) ----------
__global__ __launch_bounds__(256) void prep_kernel(
    const float* __restrict__ w0, const float* __restrict__ w1,
    const float* __restrict__ w2, const float* __restrict__ w3)
{
    int id = blockIdx.x * 256 + threadIdx.x;
    int stride = gridDim.x * 256;
    for (int i = id; i < 256 * 512; i += stride) {        // w0T[c][j] fp32 (template matvec)
        int c = i >> 9, j = i & 511;
        g_w0T[i] = (j < 256) ? w0[j * 512 + c] : w0[(j - 256) * 512 + 256 + c];
    }
    // a0 A-frags: lane l holds A[row=j=jt*16+(l&15)][k=c=k0*32+(l>>4)*8+e]
    for (int i = id; i < 32 * 8 * 64 * 8; i += stride) {
        int e = i & 7, l = (i >> 3) & 63, k0 = (i >> 9) & 7, jt = i >> 12;
        int c = k0 * 32 + ((l >> 4) * 8) + e;
        int j = jt * 16 + (l & 15);
        float v = (j < 256) ? w0[j * 512 + c] : w0[(j - 256) * 512 + 256 + c];
        unsigned short hi, lo; split_bf(v, hi, lo);
        g_wa0h[i] = hi; g_wa0l[i] = lo;
    }
    for (int i = id; i < 8 * 8 * 64 * 8; i += stride) {   // L1: 128x256
        int e = i & 7, l = (i >> 3) & 63, k0 = (i >> 9) & 7, m = i >> 12;
        int oc = m * 16 + (l & 15), c = k0 * 32 + ((l >> 4) * 8) + e;
        unsigned short hi, lo; split_bf(w1[oc * 256 + c], hi, lo);
        g_wp1h[i] = hi; g_wp1l[i] = lo;
    }
    for (int i = id; i < 4 * 4 * 64 * 8; i += stride) {   // L2: 64x128
        int e = i & 7, l = (i >> 3) & 63, k0 = (i >> 9) & 3, m = i >> 11;
        int oc = m * 16 + (l & 15), c = k0 * 32 + ((l >> 4) * 8) + e;
        unsigned short hi, lo; split_bf(w2[oc * 128 + c], hi, lo);
        g_wp2h[i] = hi; g_wp2l[i] = lo;
    }
    for (int i = id; i < 2 * 2 * 64 * 8; i += stride) {   // L3: 32x64
        int e = i & 7, l = (i >> 3) & 63, k0 = (i >> 9) & 1, m = i >> 10;
        int oc = m * 16 + (l & 15), c = k0 * 32 + ((l >> 4) * 8) + e;
        unsigned short hi, lo; split_bf(w3[oc * 64 + c], hi, lo);
        g_wp3h[i] = hi; g_wp3l[i] = lo;
    }
}

// ---------- a0 (MFMA): A0f[b,pix,j] = w0T[:,j] @ cand[b,:,pix] (3-term hi/lo, fp32 out) ----------
// block i: xcd=i&7 -> b=(i&7)*4+((i>>3)&3), jh=(i>>5)&1 (j-half), pq=i>>6 (pixel quarter of 100)
__global__ __launch_bounds__(256) void a0_kernel(
    const float* __restrict__ cand, float* __restrict__ A0f)
{
    int i = blockIdx.x;
    int b = (i & 7) * 4 + ((i >> 3) & 3);
    int jh = (i >> 5) & 1;
    int pq = i >> 6;
    int t = threadIdx.x, l = t & 63, w = t >> 6;
    int col = l & 15, q = l >> 4;

    const short8v* Ah = (const short8v*)g_wa0h;
    const short8v* Al = (const short8v*)g_wa0l;

    f32x4 acc[4][7];
#pragma unroll
    for (int mt = 0; mt < 4; ++mt)
#pragma unroll
        for (int pt = 0; pt < 7; ++pt) acc[mt][pt] = (f32x4){0.f, 0.f, 0.f, 0.f};

    for (int k0 = 0; k0 < 8; ++k0) {
        short8v ah[4], al[4];
#pragma unroll
        for (int mt = 0; mt < 4; ++mt) {
            int jt = jh * 16 + w * 4 + mt;
            ah[mt] = Ah[(jt * 8 + k0) * 64 + l];
            al[mt] = Al[(jt * 8 + k0) * 64 + l];
        }
#pragma unroll
        for (int pt = 0; pt < 7; ++pt) {
            int pixg = pq * 100 + pt * 16 + col; if (pixg > 399) pixg = 399;
            const float* cp = cand + ((size_t)(b * 256 + k0 * 32 + q * 8)) * 400 + pixg;
            float v[8];
#pragma unroll
            for (int e = 0; e < 8; ++e) v[e] = cp[(size_t)e * 400];
            short8v bh, bl;
#pragma unroll
            for (int e = 0; e < 8; ++e) {
                unsigned short hi, lo; split_bf(v[e], hi, lo);
                bh[e] = (short)hi; bl[e] = (short)lo;
            }
#pragma unroll
            for (int mt = 0; mt < 4; ++mt) {
                acc[mt][pt] = __builtin_amdgcn_mfma_f32_16x16x32_bf16(ah[mt], bh, acc[mt][pt], 0, 0, 0);
                acc[mt][pt] = __builtin_amdgcn_mfma_f32_16x16x32_bf16(ah[mt], bl, acc[mt][pt], 0, 0, 0);
                acc[mt][pt] = __builtin_amdgcn_mfma_f32_16x16x32_bf16(al[mt], bh, acc[mt][pt], 0, 0, 0);
            }
        }
    }
    // store: lane l -> C[row=q*4+rg][col], row=j-within-tile
#pragma unroll
    for (int pt = 0; pt < 7; ++pt) {
        int pixg = pq * 100 + pt * 16 + col;
        if (pixg < pq * 100 + 100) {
            float* dst = A0f + ((size_t)(b * 400) + pixg) * 512 + jh * 256 + w * 64 + q * 4;
#pragma unroll
            for (int mt = 0; mt < 4; ++mt) {
                float4 st = { acc[mt][pt][0], acc[mt][pt][1], acc[mt][pt][2], acc[mt][pt][3] };
                *(float4*)(dst + mt * 16) = st;
            }
        }
    }
}

// ---------- main: blocks 0..31 = template, 32..2367 = cand groups of P=4 patches ----------
// LDS = 32768 B -> 5 blocks/CU:
//   h0q [64 rows][64 ch] bf16 swz: hi @0 (8K), lo @8192 (8K)
//   h1 HALF [64 rows][64 oc'] bf16 swz: hi @16384 (8K), lo @24576 (8K)  (two epilogue passes)
//   m0 f32[4][256] @16384 (dead before first h1 write)
//   h2 [64][64] hi @0 / lo @8192 (overlay h0q); h3 [64][32] f32 @16384 (overlay h1hi)
//   wn f32[64] @0 (overlay h2hi); template: patchL @0 (16K), meanp @16384
__global__ __launch_bounds__(256) void main_kernel(
    const float* __restrict__ tf, const float* __restrict__ cand,
    const float* __restrict__ w4, const float* __restrict__ A0,
    float* __restrict__ out)
{
    __shared__ __align__(16) char smem[32768];
    const int OFF_H0HI = 0, OFF_H0LO = 8192;
    const int OFF_H1HI = 16384, OFF_H1LO = 24576;
    const int OFF_M0 = 16384;
    const int OFF_H2HI = 0, OFF_H2LO = 8192;
    const int OFF_H3 = 16384;

    int blk = blockIdx.x, t = threadIdx.x;
    int l = t & 63, w = t >> 6;
    int p_ = l & 15, q = l >> 4;
    int cl = t & 63, pp = t >> 6;
    bool is_tpl = blk < 32;

    float* m0_lds = (float*)(smem + OFF_M0);
    float* wn = (float*)smem;                 // valid after L3

    int b = 0, g = 0;
    int yy[4], xx[4], rr[4];
    int pixo[16];
    const float* afb = nullptr;
    float afx[16];
    float hv_t[16], tpatch[16];

    if (!is_tpl) {
        int i = blk - 32;
        int idx = (i & 7) * 292 + (i >> 3);   // 2336 = 8*292, bijective XCD swizzle
        b = idx / 73; g = idx % 73;
#pragma unroll
        for (int k = 0; k < 4; ++k) {
            int r = g * 4 + k; if (r > 288) r = 288;
            rr[k] = r; yy[k] = r / 17; xx[k] = r % 17;
        }
#pragma unroll
        for (int p = 0; p < 16; ++p)
            pixo[p] = (yy[pp] + (p >> 2)) * 20 + xx[pp] + (p & 3);
        afb = A0 + (size_t)b * 400 * 512;

        float m0v[4];
#pragma unroll
        for (int k = 0; k < 4; ++k) {
            float s = 0.f;
#pragma unroll
            for (int p = 0; p < 16; ++p) {
                int pix = (yy[k] + (p >> 2)) * 20 + xx[k] + (p & 3);
                s += afb[(size_t)pix * 512 + t];
            }
            m0v[k] = s * (1.f / 16.f);
        }
        {
            const float* axb = afb + 256 + cl;
#pragma unroll
            for (int p = 0; p < 16; ++p) afx[p] = axb[(size_t)pixo[p] * 512];
        }
#pragma unroll
        for (int k = 0; k < 4; ++k) m0_lds[k * 256 + t] = m0v[k];
        __syncthreads();
    } else {
        b = blk;
        float* meanp = (float*)(smem + 16384);
        float (*patchL)[16] = (float(*)[16])smem;
        const float* src = tf + (size_t)(b * 256 + t) * 16;
        float s = 0.f;
#pragma unroll
        for (int p = 0; p < 16; ++p) {
            float v = src[p];
            tpatch[p] = v; patchL[t][p] = v; s += v;
        }
        meanp[t] = s * (1.f / 16.f);
        __syncthreads();
        float m0 = 0.f, accp[16];
#pragma unroll
        for (int p = 0; p < 16; ++p) accp[p] = 0.f;
        for (int c = 0; c < 256; ++c) {
            float wm = g_w0T[c * 512 + t];
            float wp = g_w0T[c * 512 + 256 + t];
            m0 += wm * meanp[c];
            const float* pr = patchL[c];
#pragma unroll
            for (int p = 0; p < 16; ++p) accp[p] += wp * pr[p];
        }
#pragma unroll
        for (int p = 0; p < 16; ++p) hv_t[p] = lrelu(m0 + accp[p]);
        __syncthreads();                       // patchL reads done
        float4 z = {0.f, 0.f, 0.f, 0.f};
        float4* zp = (float4*)smem;            // zero 16K h0q region
#pragma unroll
        for (int k = 0; k < 4; ++k) zp[t + k * 256] = z;
        __syncthreads();
    }

    // ---- stage quarter 0 ----
    if (!is_tpl) {
        float m0v = m0_lds[pp * 256 + cl];
#pragma unroll
        for (int p = 0; p < 16; ++p) {
            float h = lrelu(m0v + afx[p]);
            unsigned short hi, lo; split_bf(h, hi, lo);
            int byte = (pp * 16 + p) * 128 + ((((cl >> 3) ^ (p & 7))) << 4) + (cl & 7) * 2;
            *(unsigned short*)(smem + OFF_H0HI + byte) = hi;
            *(unsigned short*)(smem + OFF_H0LO + byte) = lo;
        }
    } else if (pp == 0) {
#pragma unroll
        for (int p = 0; p < 16; ++p) {
            unsigned short hi, lo; split_bf(hv_t[p], hi, lo);
            int byte = p * 128 + ((((cl >> 3) ^ (p & 7))) << 4) + (cl & 7) * 2;
            *(unsigned short*)(smem + OFF_H0HI + byte) = hi;
            *(unsigned short*)(smem + OFF_H0LO + byte) = lo;
        }
    }
    __syncthreads();

    // ---- layer 1: 4 quarters x 2 K-steps; wave w owns M-tiles 2w,2w+1 x N-tiles 0..3 ----
    f32x4 acc0[4], acc1[4];
#pragma unroll
    for (int n = 0; n < 4; ++n) { acc0[n] = (f32x4){0.f,0.f,0.f,0.f}; acc1[n] = (f32x4){0.f,0.f,0.f,0.f}; }
    const short8v* A1h = (const short8v*)g_wp1h;
    const short8v* A1l = (const short8v*)g_wp1l;

#pragma unroll
    for (int qt = 0; qt < 4; ++qt) {
        if (!is_tpl && qt < 3) {
            const float* axb = afb + 256 + (qt + 1) * 64 + cl;
#pragma unroll
            for (int p = 0; p < 16; ++p) afx[p] = axb[(size_t)pixo[p] * 512];
        }
#pragma unroll
        for (int kk = 0; kk < 2; ++kk) {
            short8v bh[4], bl[4];
#pragma unroll
            for (int n = 0; n < 4; ++n) {
                int row = n * 16 + p_;
                int off = row * 128 + ((((kk * 4 + q) ^ (row & 7))) << 4);
                bh[n] = *(const short8v*)(smem + OFF_H0HI + off);
                bl[n] = *(const short8v*)(smem + OFF_H0LO + off);
            }
            int k0g = qt * 2 + kk;
            short8v ah0 = A1h[((2 * w) * 8 + k0g) * 64 + l];
            short8v al0 = A1l[((2 * w) * 8 + k0g) * 64 + l];
            short8v ah1 = A1h[((2 * w + 1) * 8 + k0g) * 64 + l];
            short8v al1 = A1l[((2 * w + 1) * 8 + k0g) * 64 + l];
#pragma unroll
            for (int n = 0; n < 4; ++n) {
                acc0[n] = __builtin_amdgcn_mfma_f32_16x16x32_bf16(ah0, bh[n], acc0[n], 0, 0, 0);
                acc0[n] = __builtin_amdgcn_mfma_f32_16x16x32_bf16(ah0, bl[n], acc0[n], 0, 0, 0);
                acc0[n] = __builtin_amdgcn_mfma_f32_16x16x32_bf16(al0, bh[n], acc0[n], 0, 0, 0);
                acc1[n] = __builtin_amdgcn_mfma_f32_16x16x32_bf16(ah1, bh[n], acc1[n], 0, 0, 0);
                acc1[n] = __builtin_amdgcn_mfma_f32_16x16x32_bf16(ah1, bl[n], acc1[n], 0, 0, 0);
                acc1[n] = __builtin_amdgcn_mfma_f32_16x16x32_bf16(al1, bh[n], acc1[n], 0, 0, 0);
            }
        }
        __syncthreads();                       // h0q consumed
        if (qt < 3) {
            if (!is_tpl) {
                float m0v = m0_lds[pp * 256 + (qt + 1) * 64 + cl];
#pragma unroll
                for (int p = 0; p < 16; ++p) {
                    float h = lrelu(m0v + afx[p]);
                    unsigned short hi, lo; split_bf(h, hi, lo);
                    int byte = (pp * 16 + p) * 128 + ((((cl >> 3) ^ (p & 7))) << 4) + (cl & 7) * 2;
                    *(unsigned short*)(smem + OFF_H0HI + byte) = hi;
                    *(unsigned short*)(smem + OFF_H0LO + byte) = lo;
                }
            } else if (pp == qt + 1) {
#pragma unroll
                for (int p = 0; p < 16; ++p) {
                    unsigned short hi, lo; split_bf(hv_t[p], hi, lo);
                    int byte = p * 128 + ((((cl >> 3) ^ (p & 7))) << 4) + (cl & 7) * 2;
                    *(unsigned short*)(smem + OFF_H0HI + byte) = hi;
                    *(unsigned short*)(smem + OFF_H0LO + byte) = lo;
                }
            }
            __syncthreads();
        }
    }

    // ---- layer 2 in two halves over h1 half-buffer [64 rows][64 oc'] ----
    f32x4 acc2[4];
#pragma unroll
    for (int n = 0; n < 4; ++n) acc2[n] = (f32x4){0.f,0.f,0.f,0.f};
    const short8v* A2h = (const short8v*)g_wp2h;
    const short8v* A2l = (const short8v*)g_wp2l;

#pragma unroll
    for (int half = 0; half < 2; ++half) {
        // epilogue: waves {2*half, 2*half+1} write their L1 acc (oc' = oc - half*64)
        if ((w >> 1) == half) {
#pragma unroll
            for (int m2 = 0; m2 < 2; ++m2) {
                int gp = 2 * (2 * w + m2) + (q >> 1) - half * 8;   // 0..7
#pragma unroll
                for (int n = 0; n < 4; ++n) {
                    uint2 ph, pl;
                    pack_hilo(m2 ? acc1[n] : acc0[n], ph, pl);
                    int row = n * 16 + p_;
                    int e = row * 128 + ((gp ^ (row & 7)) << 4) + (q & 1) * 8;
                    *(uint2*)(smem + OFF_H1HI + e) = ph;
                    *(uint2*)(smem + OFF_H1LO + e) = pl;
                }
            }
        }
        __syncthreads();
#pragma unroll
        for (int kf = 0; kf < 2; ++kf) {
            int kfg = half * 2 + kf;
            short8v bh[4], bl[4];
#pragma unroll
            for (int n = 0; n < 4; ++n) {
                int row = n * 16 + p_;
                int off = row * 128 + ((((kf * 4 + q) ^ (row & 7))) << 4);
                bh[n] = *(const short8v*)(smem + OFF_H1HI + off);
                bl[n] = *(const short8v*)(smem + OFF_H1LO + off);
            }
            short8v ah = A2h[(w * 4 + kfg) * 64 + l];
            short8v al = A2l[(w * 4 + kfg) * 64 + l];
#pragma unroll
            for (int n = 0; n < 4; ++n) {
                acc2[n] = __builtin_amdgcn_mfma_f32_16x16x32_bf16(ah, bh[n], acc2[n], 0, 0, 0);
                acc2[n] = __builtin_amdgcn_mfma_f32_16x16x32_bf16(ah, bl[n], acc2[n], 0, 0, 0);
                acc2[n] = __builtin_amdgcn_mfma_f32_16x16x32_bf16(al, bh[n], acc2[n], 0, 0, 0);
            }
        }
        __syncthreads();
    }
    // L2 epilogue -> h2
    {
        int gr = 2 * w + (q >> 1);
#pragma unroll
        for (int n = 0; n < 4; ++n) {
            uint2 ph, pl;
            pack_hilo(acc2[n], ph, pl);
            int row = n * 16 + p_;
            int e = row * 128 + ((gr ^ (row & 7)) << 4) + (q & 1) * 8;
            *(uint2*)(smem + OFF_H2HI + e) = ph;
            *(uint2*)(smem + OFF_H2LO + e) = pl;
        }
    }
    __syncthreads();

    // ---- layer 3: [32x64]x[64x64]; waves 0,1; h3 f32 ----
    if (w < 2) {
        f32x4 acc[4];
#pragma unroll
        for (int n = 0; n < 4; ++n) acc[n] = (f32x4){0.f,0.f,0.f,0.f};
        const short8v* A3h = (const short8v*)g_wp3h;
        const short8v* A3l = (const short8v*)g_wp3l;
#pragma unroll
        for (int k0 = 0; k0 < 2; ++k0) {
            short8v bh[4], bl[4];
#pragma unroll
            for (int n = 0; n < 4; ++n) {
                int row = n * 16 + p_;
                int off = row * 128 + ((((k0 * 4 + q) ^ (row & 7))) << 4);
                bh[n] = *(const short8v*)(smem + OFF_H2HI + off);
                bl[n] = *(const short8v*)(smem + OFF_H2LO + off);
            }
            short8v ah = A3h[(w * 2 + k0) * 64 + l];
            short8v al = A3l[(w * 2 + k0) * 64 + l];
#pragma unroll
            for (int n = 0; n < 4; ++n) {
                acc[n] = __builtin_amdgcn_mfma_f32_16x16x32_bf16(ah, bh[n], acc[n], 0, 0, 0);
                acc[n] = __builtin_amdgcn_mfma_f32_16x16x32_bf16(ah, bl[n], acc[n], 0, 0, 0);
                acc[n] = __builtin_amdgcn_mfma_f32_16x16x32_bf16(al, bh[n], acc[n], 0, 0, 0);
            }
        }
#pragma unroll
        for (int n = 0; n < 4; ++n) {
#pragma unroll
            for (int rg = 0; rg < 4; ++rg) {
                float v = lrelu(acc[n][rg]);
                int oc = w * 16 + q * 4 + rg;
                int row = n * 16 + p_;
                *(float*)(smem + OFF_H3 + row * 128 + ((oc ^ (row & 7)) << 2)) = v;
            }
        }
    }
    __syncthreads();

    // ---- layer 4 + softmax (64 scores = 4 patches x 16 pos) ----
    if (t < 64) {
        float s4 = 0.f;
#pragma unroll
        for (int c = 0; c < 32; ++c)
            s4 += w4[c] * *(const float*)(smem + OFF_H3 + t * 128 + ((c ^ (t & 7)) << 2));
        float m = s4;
#pragma unroll
        for (int msk = 8; msk; msk >>= 1) m = fmaxf(m, __shfl_xor(m, msk));
        float e = __expf(s4 - m), sum = e;
#pragma unroll
        for (int msk = 8; msk; msk >>= 1) sum += __shfl_xor(sum, msk);
        wn[t] = e / sum;
    }
    __syncthreads();

    // ---- weighted pooling + store ----
    if (!is_tpl) {
        const float* cb = cand + (size_t)(b * 256 + t) * 400;
#pragma unroll
        for (int k = 0; k < 4; ++k) {
            float acc = 0.f;
#pragma unroll
            for (int p = 0; p < 16; ++p)
                acc += cb[(yy[k] + (p >> 2)) * 20 + xx[k] + (p & 3)] * wn[k * 16 + p];
            out[8704 + (size_t)(b * 256 + t) * 289 + rr[k]] = acc;
        }
    } else {
        float acc = 0.f;
#pragma unroll
        for (int p = 0; p < 16; ++p) acc += tpatch[p] * wn[p];
        out[b * 272 + t] = acc;
        if (t < 16) out[b * 272 + 256 + t] = wn[t];
    }
}

// ---------- launch ----------
extern "C" void kernel_launch(void* const* d_in, const int* in_sizes, int n_in,
                              void* d_out, int out_size, void* d_ws, size_t ws_size,
                              hipStream_t stream)
{
    const float* tf = (const float*)d_in[0];
    const float* cf = (const float*)d_in[1];
    const float* w0 = (const float*)d_in[2];
    const float* w1 = (const float*)d_in[3];
    const float* w2 = (const float*)d_in[4];
    const float* w3 = (const float*)d_in[5];
    const float* w4 = (const float*)d_in[6];
    float* out = (float*)d_out;
    float* A0f = (float*)d_ws;   // 32*400*512 fp32 = 26.2 MB (proven to fit)

    prep_kernel<<<680, 256, 0, stream>>>(w0, w1, w2, w3);
    a0_kernel<<<256, 256, 0, stream>>>(cf, A0f);
    main_kernel<<<32 + 584 * 4, 256, 0, stream>>>(tf, cf, w4, A0f, out);
}